// Round 2
// baseline (1817.659 us; speedup 1.0000x reference)
//
#include <hip/hip_runtime.h>
#include <stdint.h>

typedef __attribute__((ext_vector_type(4))) int i32x4;

typedef const __attribute__((address_space(1))) void gvoid_t;
typedef __attribute__((address_space(3))) void lvoid_t;

#define GLD16(g, l) __builtin_amdgcn_global_load_lds((gvoid_t*)(g), (lvoid_t*)(l), 16, 0, 0)
#define FENCE() asm volatile("" ::: "memory")

__device__ inline int q1mul(float x, float r) {
    return (int)fminf(fmaxf(rintf(x * r), -128.f), 127.f);
}
__device__ inline int q1div(float x, float s) {
    return (int)fminf(fmaxf(rintf(x / s), -128.f), 127.f);
}
__device__ inline int pack4(float4 v, float r) {
    return (q1mul(v.x, r) & 255) | ((q1mul(v.y, r) & 255) << 8) |
           ((q1mul(v.z, r) & 255) << 16) | ((q1mul(v.w, r) & 255) << 24);
}

// ---------------- global absmax ----------------
__global__ void k_absmax(const float* __restrict__ x, size_t n4, unsigned int* __restrict__ out) {
    size_t S = (size_t)gridDim.x * blockDim.x;
    size_t i = (size_t)blockIdx.x * blockDim.x + threadIdx.x;
    const float4* x4 = (const float4*)x;
    float m = 0.f;
    for (; i + 3 * S < n4; i += 4 * S) {
        float4 v0 = x4[i], v1 = x4[i + S], v2 = x4[i + 2 * S], v3 = x4[i + 3 * S];
        m = fmaxf(m, fmaxf(fmaxf(fabsf(v0.x), fabsf(v0.y)), fmaxf(fabsf(v0.z), fabsf(v0.w))));
        m = fmaxf(m, fmaxf(fmaxf(fabsf(v1.x), fabsf(v1.y)), fmaxf(fabsf(v1.z), fabsf(v1.w))));
        m = fmaxf(m, fmaxf(fmaxf(fabsf(v2.x), fabsf(v2.y)), fmaxf(fabsf(v2.z), fabsf(v2.w))));
        m = fmaxf(m, fmaxf(fmaxf(fabsf(v3.x), fabsf(v3.y)), fmaxf(fabsf(v3.z), fabsf(v3.w))));
    }
    for (; i < n4; i += S) {
        float4 v = x4[i];
        m = fmaxf(m, fmaxf(fmaxf(fabsf(v.x), fabsf(v.y)), fmaxf(fabsf(v.z), fabsf(v.w))));
    }
    #pragma unroll
    for (int off = 32; off > 0; off >>= 1) m = fmaxf(m, __shfl_xor(m, off, 64));
    if ((threadIdx.x & 63) == 0) atomicMax(out, __float_as_uint(m));
}

// ---------------- scale finalize ----------------
__global__ void k_scale(const float* __restrict__ clip, const unsigned int* __restrict__ maxbits,
                        float* __restrict__ s_out) {
    float m = __uint_as_float(*maxbits);
    float sig = 1.f / (1.f + expf(-clip[0]));
    float s = sig * m / 127.f;
    s_out[0] = s;
    s_out[1] = 1.f / s;
}

// ---------------- quantize fp32 -> packed int8 (16 elems/thread/iter) ----------------
__global__ void k_quant_f32_i8(const float* __restrict__ in, int4* __restrict__ out,
                               const float* __restrict__ sptr, size_t n16) {
    float r = sptr[1];
    size_t S = (size_t)gridDim.x * blockDim.x;
    size_t i = (size_t)blockIdx.x * blockDim.x + threadIdx.x;
    const float4* in4 = (const float4*)in;
    for (; i < n16; i += S) {
        float4 v0 = in4[4 * i], v1 = in4[4 * i + 1], v2 = in4[4 * i + 2], v3 = in4[4 * i + 3];
        int4 o;
        o.x = pack4(v0, r); o.y = pack4(v1, r); o.z = pack4(v2, r); o.w = pack4(v3, r);
        out[i] = o;
    }
}

// ---------------- per-row weight quantization ----------------
__global__ void k_quant_w_i8(const float* __restrict__ W, int8_t* __restrict__ Q,
                             float* __restrict__ srow, int cols) {
    int row = blockIdx.x;
    const float* w = W + (size_t)row * cols;
    float m = 0.f;
    for (int c = threadIdx.x; c < cols; c += 256) m = fmaxf(m, fabsf(w[c]));
    #pragma unroll
    for (int off = 32; off > 0; off >>= 1) m = fmaxf(m, __shfl_xor(m, off, 64));
    __shared__ float red[4];
    if ((threadIdx.x & 63) == 0) red[threadIdx.x >> 6] = m;
    __syncthreads();
    if (threadIdx.x == 0) {
        float mm = fmaxf(fmaxf(red[0], red[1]), fmaxf(red[2], red[3]));
        red[0] = mm / 127.f;
        srow[row] = mm / 127.f;
    }
    __syncthreads();
    float s = red[0];
    for (int c = threadIdx.x; c < cols; c += 256)
        Q[(size_t)row * cols + c] = (int8_t)q1div(w[c], s);
}

// ================= GEMM1 fused (gate+up), i8 MFMA =================
// m97-mirror: tile 128(M) x 64(N of each of gate/up), BK=64, 256 thr (4 waves 2Mx2N),
// wave tile 64x32(g)+64x32(u), acc=64 VGPR, 2-buffer LDS 32 KB -> 4 blocks/CU.
__global__ __launch_bounds__(256, 4) void k_gemm1_i8(
    const int8_t* __restrict__ Aq, const int8_t* __restrict__ Bg, const int8_t* __restrict__ Bu,
    const float* __restrict__ sg, const float* __restrict__ su, const float* __restrict__ sx,
    float* __restrict__ Hout, unsigned int* __restrict__ maxh)
{
    constexpr int K = 1024, N = 2816, NT = K / 64, TB = 16384;
    __shared__ int8_t lds[2 * TB];   // per buffer: A[128][64] | Bg[64][64] | Bu[64][64]

    const int ntn = N / 64;                          // 44
    // XCD-chunked bijective swizzle (grid = 22528 = 8*2816)
    const int chunk = gridDim.x >> 3;
    const int wg = ((int)blockIdx.x & 7) * chunk + ((int)blockIdx.x >> 3);
    const int mt = wg / ntn, nt = wg % ntn;
    const int m0 = mt * 128, n0 = nt * 64;
    const int tid = threadIdx.x;
    const int wid = tid >> 6, lane = tid & 63;
    const int wm = wid >> 1, wn = wid & 1;
    const int lr = lane & 15, lk = lane >> 4;

    // staging: linear LDS dest, inverse-swizzled global source (rule #21)
    const int srow = tid >> 2;                       // 0..63
    const int scol = ((tid & 3) ^ ((srow >> 1) & 3)) << 4;
    const int8_t* gA0 = Aq + (size_t)(m0 + srow) * K + scol;
    const int8_t* gA1 = gA0 + (size_t)64 * K;        // rows 64..127 (same swizzle: (row+64)>>1 mod 4 unchanged)
    const int8_t* gG  = Bg + (size_t)(n0 + srow) * K + scol;
    const int8_t* gU  = Bu + (size_t)(n0 + srow) * K + scol;
    const int ldst = wid << 10;                      // wave-uniform 1 KB chunk

    // fragment read offsets (swizzled) — layout verified in round-1 kernel
    const int swz = (lk ^ ((lr >> 1) & 3)) << 4;
    int offA[4], offG[2], offU[2];
    #pragma unroll
    for (int mi = 0; mi < 4; ++mi) offA[mi] = (wm * 64 + mi * 16 + lr) * 64 + swz;
    #pragma unroll
    for (int ni = 0; ni < 2; ++ni) {
        offG[ni] = 8192  + (wn * 32 + ni * 16 + lr) * 64 + swz;
        offU[ni] = 12288 + (wn * 32 + ni * 16 + lr) * 64 + swz;
    }

    i32x4 accg[4][2] = {};
    i32x4 accu[4][2] = {};

    auto stage = [&](int t, int b) {
        const size_t k0 = (size_t)t * 64;
        int8_t* L = &lds[b * TB];
        GLD16(gA0 + k0, L + ldst);
        GLD16(gA1 + k0, L + 4096  + ldst);
        GLD16(gG  + k0, L + 8192  + ldst);
        GLD16(gU  + k0, L + 12288 + ldst);
    };

    stage(0, 0);

    for (int t = 0; t < NT; ++t) {
        // drain my 4 staging loads for tile t (issued last iteration; 1 full compute phase in flight)
        asm volatile("s_waitcnt vmcnt(0) lgkmcnt(0)" ::: "memory");
        FENCE(); __builtin_amdgcn_s_barrier(); FENCE();
        if (t + 1 < NT) stage(t + 1, (t + 1) & 1);   // after barrier: prev readers of target buffer done
        const int8_t* L = &lds[(t & 1) * TB];
        i32x4 a[4], bgf[2], buf_[2];
        #pragma unroll
        for (int mi = 0; mi < 4; ++mi) a[mi] = *(const i32x4*)(L + offA[mi]);
        #pragma unroll
        for (int ni = 0; ni < 2; ++ni) {
            bgf[ni]  = *(const i32x4*)(L + offG[ni]);
            buf_[ni] = *(const i32x4*)(L + offU[ni]);
        }
        __builtin_amdgcn_s_setprio(1);
        #pragma unroll
        for (int mi = 0; mi < 4; ++mi) {
            #pragma unroll
            for (int ni = 0; ni < 2; ++ni) {
                accg[mi][ni] = __builtin_amdgcn_mfma_i32_16x16x64_i8(a[mi], bgf[ni], accg[mi][ni], 0, 0, 0);
                accu[mi][ni] = __builtin_amdgcn_mfma_i32_16x16x64_i8(a[mi], buf_[ni], accu[mi][ni], 0, 0, 0);
            }
        }
        __builtin_amdgcn_s_setprio(0);
    }

    // epilogue: SwiGLU + h write + global max
    const float s_x = sx[0];
    float lmax = 0.f;
    #pragma unroll
    for (int ni = 0; ni < 2; ++ni) {
        const int n = n0 + wn * 32 + ni * 16 + lr;
        const float fg = s_x * sg[n];
        const float fu = s_x * su[n];
        #pragma unroll
        for (int mi = 0; mi < 4; ++mi) {
            const int mb = m0 + wm * 64 + mi * 16 + lk * 4;
            #pragma unroll
            for (int r = 0; r < 4; ++r) {
                float g = (float)accg[mi][ni][r] * fg;
                float u = (float)accu[mi][ni][r] * fu;
                float h = g * u / (1.f + expf(-g));
                Hout[(size_t)(mb + r) * N + n] = h;
                lmax = fmaxf(lmax, fabsf(h));
            }
        }
    }
    #pragma unroll
    for (int off = 32; off > 0; off >>= 1) lmax = fmaxf(lmax, __shfl_xor(lmax, off, 64));
    if (lane == 0) atomicMax(maxh, __float_as_uint(lmax));
}

// ================= GEMM2: out = (q_h @ q_wd^T) * s_h * s_wd[n] =================
// tile 128x128, BK=64, 256 thr (4 waves 2Mx2N), wave tile 64x64, acc=64, 2-buffer 32 KB.
__global__ __launch_bounds__(256, 4) void k_gemm2_i8(
    const int8_t* __restrict__ Aq, const int8_t* __restrict__ Bw,
    const float* __restrict__ sw, const float* __restrict__ sh,
    float* __restrict__ Out)
{
    constexpr int K = 2816, N = 1024, NT = K / 64, TB = 16384;
    __shared__ int8_t lds[2 * TB];   // per buffer: A[128][64] | B[128][64]

    // XCD-chunked bijective swizzle (grid = 4096 = 8*512)
    const int chunk = gridDim.x >> 3;
    const int wg = ((int)blockIdx.x & 7) * chunk + ((int)blockIdx.x >> 3);
    const int mt = wg >> 3, nt = wg & 7;             // ntn = 1024/128 = 8
    const int m0 = mt * 128, n0 = nt * 128;
    const int tid = threadIdx.x;
    const int wid = tid >> 6, lane = tid & 63;
    const int wm = wid >> 1, wn = wid & 1;
    const int lr = lane & 15, lk = lane >> 4;

    const int srow = tid >> 2;                       // 0..63
    const int scol = ((tid & 3) ^ ((srow >> 1) & 3)) << 4;
    const int8_t* gA0 = Aq + (size_t)(m0 + srow) * K + scol;
    const int8_t* gA1 = gA0 + (size_t)64 * K;
    const int8_t* gB0 = Bw + (size_t)(n0 + srow) * K + scol;
    const int8_t* gB1 = gB0 + (size_t)64 * K;
    const int ldst = wid << 10;

    const int swz = (lk ^ ((lr >> 1) & 3)) << 4;
    int offA[4], offB[4];
    #pragma unroll
    for (int mi = 0; mi < 4; ++mi) offA[mi] = (wm * 64 + mi * 16 + lr) * 64 + swz;
    #pragma unroll
    for (int ni = 0; ni < 4; ++ni) offB[ni] = 8192 + (wn * 64 + ni * 16 + lr) * 64 + swz;

    i32x4 acc[4][4] = {};

    auto stage = [&](int t, int b) {
        const size_t k0 = (size_t)t * 64;
        int8_t* L = &lds[b * TB];
        GLD16(gA0 + k0, L + ldst);
        GLD16(gA1 + k0, L + 4096  + ldst);
        GLD16(gB0 + k0, L + 8192  + ldst);
        GLD16(gB1 + k0, L + 12288 + ldst);
    };

    stage(0, 0);

    for (int t = 0; t < NT; ++t) {
        asm volatile("s_waitcnt vmcnt(0) lgkmcnt(0)" ::: "memory");
        FENCE(); __builtin_amdgcn_s_barrier(); FENCE();
        if (t + 1 < NT) stage(t + 1, (t + 1) & 1);
        const int8_t* L = &lds[(t & 1) * TB];
        i32x4 a[4], b[4];
        #pragma unroll
        for (int mi = 0; mi < 4; ++mi) a[mi] = *(const i32x4*)(L + offA[mi]);
        #pragma unroll
        for (int ni = 0; ni < 4; ++ni) b[ni] = *(const i32x4*)(L + offB[ni]);
        __builtin_amdgcn_s_setprio(1);
        #pragma unroll
        for (int mi = 0; mi < 4; ++mi) {
            #pragma unroll
            for (int ni = 0; ni < 4; ++ni)
                acc[mi][ni] = __builtin_amdgcn_mfma_i32_16x16x64_i8(a[mi], b[ni], acc[mi][ni], 0, 0, 0);
        }
        __builtin_amdgcn_s_setprio(0);
    }

    const float s_h = sh[0];
    #pragma unroll
    for (int ni = 0; ni < 4; ++ni) {
        const int n = n0 + wn * 64 + ni * 16 + lr;
        const float f = s_h * sw[n];
        #pragma unroll
        for (int mi = 0; mi < 4; ++mi) {
            const int mb = m0 + wm * 64 + mi * 16 + lk * 4;
            #pragma unroll
            for (int r = 0; r < 4; ++r)
                Out[(size_t)(mb + r) * N + n] = (float)acc[mi][ni][r] * f;
        }
    }
}

extern "C" void kernel_launch(void* const* d_in, const int* in_sizes, int n_in,
                              void* d_out, int out_size, void* d_ws, size_t ws_size,
                              hipStream_t stream) {
    const float* x       = (const float*)d_in[0];
    const float* clip_x  = (const float*)d_in[1];
    const float* clip_dn = (const float*)d_in[2];
    const float* w_gate  = (const float*)d_in[3];
    const float* w_up    = (const float*)d_in[4];
    const float* w_down  = (const float*)d_in[5];
    float* out = (float*)d_out;

    const int Hd = 1024, Id = 2816;
    const int M = in_sizes[0] / Hd;                  // 65536
    const size_t nx = (size_t)M * Hd;
    const size_t nh = (size_t)M * Id;

    char* ws = (char*)d_ws;
    size_t off = 0;
    auto alloc = [&](size_t bytes) -> char* {
        char* p = ws + off;
        off = (off + bytes + 255) & ~(size_t)255;
        return p;
    };
    unsigned int* max_slots = (unsigned int*)alloc(8);   // [0]=max|x|, [1]=max|h|
    float* sxp = (float*)alloc(8);                       // [0]=scale, [1]=1/scale
    float* shp = (float*)alloc(8);
    int8_t* qx  = (int8_t*)alloc(nx);
    int8_t* qwg = (int8_t*)alloc((size_t)Id * Hd);
    int8_t* qwu = (int8_t*)alloc((size_t)Id * Hd);
    int8_t* qwd = (int8_t*)alloc((size_t)Hd * Id);
    float* swg = (float*)alloc((size_t)Id * 4);
    float* swu = (float*)alloc((size_t)Id * 4);
    float* swd = (float*)alloc((size_t)Hd * 4);
    int8_t* qh = (int8_t*)alloc(nh);
    float* hbuf = (float*)alloc(nh * 4);

    hipMemsetAsync(max_slots, 0, 8, stream);

    k_absmax<<<4096, 256, 0, stream>>>(x, nx / 4, &max_slots[0]);
    k_scale<<<1, 1, 0, stream>>>(clip_x, &max_slots[0], sxp);
    k_quant_f32_i8<<<2048, 256, 0, stream>>>(x, (int4*)qx, sxp, nx / 16);
    k_quant_w_i8<<<Id, 256, 0, stream>>>(w_gate, qwg, swg, Hd);
    k_quant_w_i8<<<Id, 256, 0, stream>>>(w_up, qwu, swu, Hd);
    k_quant_w_i8<<<Hd, 256, 0, stream>>>(w_down, qwd, swd, Id);

    k_gemm1_i8<<<(M / 128) * (Id / 64), 256, 0, stream>>>(qx, qwg, qwu, swg, swu, sxp,
                                                          hbuf, &max_slots[1]);
    k_scale<<<1, 1, 0, stream>>>(clip_dn, &max_slots[1], shp);
    k_quant_f32_i8<<<4096, 256, 0, stream>>>(hbuf, (int4*)qh, shp, nh / 16);

    k_gemm2_i8<<<(M / 128) * (Hd / 128), 256, 0, stream>>>(qh, qwd, swd, shp, out);
}

// Round 3
// 1381.711 us; speedup vs baseline: 1.3155x; 1.3155x over previous
//
#include <hip/hip_runtime.h>
#include <stdint.h>

typedef __attribute__((ext_vector_type(4))) int i32x4;

typedef const __attribute__((address_space(1))) void gvoid_t;
typedef __attribute__((address_space(3))) void lvoid_t;

#define GLD16(g, l) __builtin_amdgcn_global_load_lds((gvoid_t*)(g), (lvoid_t*)(l), 16, 0, 0)
#define FENCE() asm volatile("" ::: "memory")
#define BARRIER() do { FENCE(); __builtin_amdgcn_s_barrier(); FENCE(); } while (0)

__device__ inline int q1mul(float x, float r) {
    return (int)fminf(fmaxf(rintf(x * r), -128.f), 127.f);
}
__device__ inline int q1div(float x, float s) {
    return (int)fminf(fmaxf(rintf(x / s), -128.f), 127.f);
}
__device__ inline int pack4(float4 v, float r) {
    return (q1mul(v.x, r) & 255) | ((q1mul(v.y, r) & 255) << 8) |
           ((q1mul(v.z, r) & 255) << 16) | ((q1mul(v.w, r) & 255) << 24);
}

// ---------------- global absmax ----------------
__global__ void k_absmax(const float* __restrict__ x, size_t n4, unsigned int* __restrict__ out) {
    size_t S = (size_t)gridDim.x * blockDim.x;
    size_t i = (size_t)blockIdx.x * blockDim.x + threadIdx.x;
    const float4* x4 = (const float4*)x;
    float m = 0.f;
    for (; i + 3 * S < n4; i += 4 * S) {
        float4 v0 = x4[i], v1 = x4[i + S], v2 = x4[i + 2 * S], v3 = x4[i + 3 * S];
        m = fmaxf(m, fmaxf(fmaxf(fabsf(v0.x), fabsf(v0.y)), fmaxf(fabsf(v0.z), fabsf(v0.w))));
        m = fmaxf(m, fmaxf(fmaxf(fabsf(v1.x), fabsf(v1.y)), fmaxf(fabsf(v1.z), fabsf(v1.w))));
        m = fmaxf(m, fmaxf(fmaxf(fabsf(v2.x), fabsf(v2.y)), fmaxf(fabsf(v2.z), fabsf(v2.w))));
        m = fmaxf(m, fmaxf(fmaxf(fabsf(v3.x), fabsf(v3.y)), fmaxf(fabsf(v3.z), fabsf(v3.w))));
    }
    for (; i < n4; i += S) {
        float4 v = x4[i];
        m = fmaxf(m, fmaxf(fmaxf(fabsf(v.x), fabsf(v.y)), fmaxf(fabsf(v.z), fabsf(v.w))));
    }
    #pragma unroll
    for (int off = 32; off > 0; off >>= 1) m = fmaxf(m, __shfl_xor(m, off, 64));
    if ((threadIdx.x & 63) == 0) atomicMax(out, __float_as_uint(m));
}

// ---------------- scale finalize ----------------
__global__ void k_scale(const float* __restrict__ clip, const unsigned int* __restrict__ maxbits,
                        float* __restrict__ s_out) {
    float m = __uint_as_float(*maxbits);
    float sig = 1.f / (1.f + expf(-clip[0]));
    float s = sig * m / 127.f;
    s_out[0] = s;
    s_out[1] = 1.f / s;
}

// ---------------- quantize fp32 -> packed int8 (16 elems/thread/iter) ----------------
__global__ void k_quant_f32_i8(const float* __restrict__ in, int4* __restrict__ out,
                               const float* __restrict__ sptr, size_t n16) {
    float r = sptr[1];
    size_t S = (size_t)gridDim.x * blockDim.x;
    size_t i = (size_t)blockIdx.x * blockDim.x + threadIdx.x;
    const float4* in4 = (const float4*)in;
    for (; i < n16; i += S) {
        float4 v0 = in4[4 * i], v1 = in4[4 * i + 1], v2 = in4[4 * i + 2], v3 = in4[4 * i + 3];
        int4 o;
        o.x = pack4(v0, r); o.y = pack4(v1, r); o.z = pack4(v2, r); o.w = pack4(v3, r);
        out[i] = o;
    }
}

// ---------------- per-row weight quantization ----------------
__global__ void k_quant_w_i8(const float* __restrict__ W, int8_t* __restrict__ Q,
                             float* __restrict__ srow, int cols) {
    int row = blockIdx.x;
    const float* w = W + (size_t)row * cols;
    float m = 0.f;
    for (int c = threadIdx.x; c < cols; c += 256) m = fmaxf(m, fabsf(w[c]));
    #pragma unroll
    for (int off = 32; off > 0; off >>= 1) m = fmaxf(m, __shfl_xor(m, off, 64));
    __shared__ float red[4];
    if ((threadIdx.x & 63) == 0) red[threadIdx.x >> 6] = m;
    __syncthreads();
    if (threadIdx.x == 0) {
        float mm = fmaxf(fmaxf(red[0], red[1]), fmaxf(red[2], red[3]));
        red[0] = mm / 127.f;
        srow[row] = mm / 127.f;
    }
    __syncthreads();
    float s = red[0];
    for (int c = threadIdx.x; c < cols; c += 256)
        Q[(size_t)row * cols + c] = (int8_t)q1div(w[c], s);
}

// ================= GEMM1 fused (gate+up), i8 MFMA, 8-phase-style counted-vmcnt =================
// Tile 256(M) x 128(N of each of gate/up), BK=64, 512 thr (8 waves 2Mx4N), wave 128x32(g)+128x32(u).
// 3-buffer LDS ring (96 KB); 2 sub-phases per K-tile, 16 MFMA each; vmcnt(4) once per K-tile.
__global__ __launch_bounds__(512, 2) void k_gemm1_i8(
    const int8_t* __restrict__ Aq, const int8_t* __restrict__ Bg, const int8_t* __restrict__ Bu,
    const float* __restrict__ sg, const float* __restrict__ su, const float* __restrict__ sx,
    float* __restrict__ Hout, unsigned int* __restrict__ maxh)
{
    constexpr int K = 1024, N = 2816, NT = K / 64, TB = 32768;
    __shared__ int8_t lds[3 * TB];   // per buffer: A[256][64] 16K | Bg[128][64] 8K | Bu[128][64] 8K

    const int ntn = N / 128;                         // 22
    // XCD-chunked bijective swizzle (grid = 5632 = 8*704)
    const int chunk = gridDim.x >> 3;
    const int wg = ((int)blockIdx.x & 7) * chunk + ((int)blockIdx.x >> 3);
    const int mt = wg / ntn, nt = wg % ntn;
    const int m0 = mt * 256, n0 = nt * 128;
    const int tid = threadIdx.x;
    const int wid = tid >> 6, lane = tid & 63;
    const int wm = wid >> 2, wn = wid & 3;
    const int lr = lane & 15, lk = lane >> 4;

    // staging: linear LDS dest, inverse-swizzled global source (rule #21)
    const int srow = tid >> 2;                       // 0..127
    const int scol = ((tid & 3) ^ ((srow >> 1) & 3)) << 4;
    const int8_t* gA0 = Aq + (size_t)(m0 + srow) * K + scol;
    const int8_t* gA1 = gA0 + (size_t)128 * K;
    const int8_t* gG  = Bg + (size_t)(n0 + srow) * K + scol;
    const int8_t* gU  = Bu + (size_t)(n0 + srow) * K + scol;
    const int ldst = wid << 10;                      // wave-uniform 1 KB chunk within each 8 KB region

    // fragment read offsets (swizzled) — layout verified round 1
    const int swz = (lk ^ ((lr >> 1) & 3)) << 4;
    int offA[8], offG[2], offU[2];
    #pragma unroll
    for (int mi = 0; mi < 8; ++mi) offA[mi] = (wm * 128 + mi * 16 + lr) * 64 + swz;
    #pragma unroll
    for (int ni = 0; ni < 2; ++ni) {
        offG[ni] = 16384 + (wn * 32 + ni * 16 + lr) * 64 + swz;
        offU[ni] = 24576 + (wn * 32 + ni * 16 + lr) * 64 + swz;
    }

    i32x4 accg[8][2] = {};
    i32x4 accu[8][2] = {};

    // prologue: fully stage tiles 0 and 1 (issue order: A0,A1,G,U per tile)
    {
        int8_t* L0 = &lds[0];
        GLD16(gA0, L0 + ldst);          GLD16(gA1, L0 + 8192 + ldst);
        GLD16(gG,  L0 + 16384 + ldst);  GLD16(gU,  L0 + 24576 + ldst);
        int8_t* L1 = &lds[TB];
        GLD16(gA0 + 64, L1 + ldst);          GLD16(gA1 + 64, L1 + 8192 + ldst);
        GLD16(gG  + 64, L1 + 16384 + ldst);  GLD16(gU  + 64, L1 + 24576 + ldst);
    }
    asm volatile("s_waitcnt vmcnt(4)" ::: "memory");   // tile 0 landed, tile 1 in flight
    BARRIER();

    for (int t = 0; t < NT; ++t) {
        const int8_t* L = &lds[(t % 3) * TB];
        int8_t* Ls = &lds[((t + 2) % 3) * TB];
        const size_t k2 = (size_t)(t + 2) * 64;
        const bool st = (t + 2 < NT);

        // ---- phase 0: A frags 0-3 + all B frags; stage A-halves of t+2; MFMA mi 0-3 ----
        i32x4 a[4], bgf[2], buf_[2];
        #pragma unroll
        for (int mi = 0; mi < 4; ++mi) a[mi] = *(const i32x4*)(L + offA[mi]);
        #pragma unroll
        for (int ni = 0; ni < 2; ++ni) {
            bgf[ni]  = *(const i32x4*)(L + offG[ni]);
            buf_[ni] = *(const i32x4*)(L + offU[ni]);
        }
        if (st) { GLD16(gA0 + k2, Ls + ldst); GLD16(gA1 + k2, Ls + 8192 + ldst); }
        BARRIER();
        __builtin_amdgcn_s_setprio(1);
        #pragma unroll
        for (int mi = 0; mi < 4; ++mi) {
            #pragma unroll
            for (int ni = 0; ni < 2; ++ni) {
                accg[mi][ni] = __builtin_amdgcn_mfma_i32_16x16x64_i8(a[mi], bgf[ni], accg[mi][ni], 0, 0, 0);
                accu[mi][ni] = __builtin_amdgcn_mfma_i32_16x16x64_i8(a[mi], buf_[ni], accu[mi][ni], 0, 0, 0);
            }
        }
        __builtin_amdgcn_s_setprio(0);
        BARRIER();

        // ---- phase 1: A frags 4-7; stage B-halves of t+2; MFMA mi 4-7; counted vmcnt ----
        i32x4 a2[4];
        #pragma unroll
        for (int mi = 0; mi < 4; ++mi) a2[mi] = *(const i32x4*)(L + offA[4 + mi]);
        if (st) { GLD16(gG + k2, Ls + 16384 + ldst); GLD16(gU + k2, Ls + 24576 + ldst); }
        BARRIER();
        __builtin_amdgcn_s_setprio(1);
        #pragma unroll
        for (int mi = 0; mi < 4; ++mi) {
            #pragma unroll
            for (int ni = 0; ni < 2; ++ni) {
                accg[4 + mi][ni] = __builtin_amdgcn_mfma_i32_16x16x64_i8(a2[mi], bgf[ni], accg[4 + mi][ni], 0, 0, 0);
                accu[4 + mi][ni] = __builtin_amdgcn_mfma_i32_16x16x64_i8(a2[mi], buf_[ni], accu[4 + mi][ni], 0, 0, 0);
            }
        }
        __builtin_amdgcn_s_setprio(0);
        // tile boundary: tile t+1's 4 loads must land; keep tile t+2's 4 in flight
        if (st) { asm volatile("s_waitcnt vmcnt(4)" ::: "memory"); }
        else    { asm volatile("s_waitcnt vmcnt(0)" ::: "memory"); }
        BARRIER();
    }

    // epilogue: SwiGLU + h write + global max (verified round 1)
    const float s_x = sx[0];
    float lmax = 0.f;
    #pragma unroll
    for (int ni = 0; ni < 2; ++ni) {
        const int n = n0 + wn * 32 + ni * 16 + lr;
        const float fg = s_x * sg[n];
        const float fu = s_x * su[n];
        #pragma unroll
        for (int mi = 0; mi < 8; ++mi) {
            const int mb = m0 + wm * 128 + mi * 16 + lk * 4;
            #pragma unroll
            for (int r = 0; r < 4; ++r) {
                float g = (float)accg[mi][ni][r] * fg;
                float u = (float)accu[mi][ni][r] * fu;
                float h = g * u / (1.f + expf(-g));
                Hout[(size_t)(mb + r) * N + n] = h;
                lmax = fmaxf(lmax, fabsf(h));
            }
        }
    }
    #pragma unroll
    for (int off = 32; off > 0; off >>= 1) lmax = fmaxf(lmax, __shfl_xor(lmax, off, 64));
    if (lane == 0) atomicMax(maxh, __float_as_uint(lmax));
}

// ================= GEMM2: out = (q_h @ q_wd^T) * s_h * s_wd[n], same schedule =================
// Tile 256x256, BK=64, 512 thr (8 waves 2Mx4N), wave 128x64. 3-buffer ring 96 KB.
__global__ __launch_bounds__(512, 2) void k_gemm2_i8(
    const int8_t* __restrict__ Aq, const int8_t* __restrict__ Bw,
    const float* __restrict__ sw, const float* __restrict__ sh,
    float* __restrict__ Out)
{
    constexpr int K = 2816, N = 1024, NT = K / 64, TB = 32768;
    __shared__ int8_t lds[3 * TB];   // per buffer: A[256][64] 16K | B[256][64] 16K

    // XCD-chunked bijective swizzle (grid = 1024 = 8*128)
    const int chunk = gridDim.x >> 3;
    const int wg = ((int)blockIdx.x & 7) * chunk + ((int)blockIdx.x >> 3);
    const int mt = wg >> 2, nt = wg & 3;             // ntn = 1024/256 = 4
    const int m0 = mt * 256, n0 = nt * 256;
    const int tid = threadIdx.x;
    const int wid = tid >> 6, lane = tid & 63;
    const int wm = wid >> 2, wn = wid & 3;
    const int lr = lane & 15, lk = lane >> 4;

    const int srow = tid >> 2;                       // 0..127
    const int scol = ((tid & 3) ^ ((srow >> 1) & 3)) << 4;
    const int8_t* gA0 = Aq + (size_t)(m0 + srow) * K + scol;
    const int8_t* gA1 = gA0 + (size_t)128 * K;
    const int8_t* gB0 = Bw + (size_t)(n0 + srow) * K + scol;
    const int8_t* gB1 = gB0 + (size_t)128 * K;
    const int ldst = wid << 10;

    const int swz = (lk ^ ((lr >> 1) & 3)) << 4;
    int offA[8], offB[4];
    #pragma unroll
    for (int mi = 0; mi < 8; ++mi) offA[mi] = (wm * 128 + mi * 16 + lr) * 64 + swz;
    #pragma unroll
    for (int ni = 0; ni < 4; ++ni) offB[ni] = 16384 + (wn * 64 + ni * 16 + lr) * 64 + swz;

    i32x4 acc[8][4] = {};

    {
        int8_t* L0 = &lds[0];
        GLD16(gA0, L0 + ldst);          GLD16(gA1, L0 + 8192 + ldst);
        GLD16(gB0, L0 + 16384 + ldst);  GLD16(gB1, L0 + 24576 + ldst);
        int8_t* L1 = &lds[TB];
        GLD16(gA0 + 64, L1 + ldst);          GLD16(gA1 + 64, L1 + 8192 + ldst);
        GLD16(gB0 + 64, L1 + 16384 + ldst);  GLD16(gB1 + 64, L1 + 24576 + ldst);
    }
    asm volatile("s_waitcnt vmcnt(4)" ::: "memory");
    BARRIER();

    for (int t = 0; t < NT; ++t) {
        const int8_t* L = &lds[(t % 3) * TB];
        int8_t* Ls = &lds[((t + 2) % 3) * TB];
        const size_t k2 = (size_t)(t + 2) * 64;
        const bool st = (t + 2 < NT);

        // ---- phase 0 ----
        i32x4 a[4], b[4];
        #pragma unroll
        for (int mi = 0; mi < 4; ++mi) a[mi] = *(const i32x4*)(L + offA[mi]);
        #pragma unroll
        for (int ni = 0; ni < 4; ++ni) b[ni] = *(const i32x4*)(L + offB[ni]);
        if (st) { GLD16(gA0 + k2, Ls + ldst); GLD16(gA1 + k2, Ls + 8192 + ldst); }
        BARRIER();
        __builtin_amdgcn_s_setprio(1);
        #pragma unroll
        for (int mi = 0; mi < 4; ++mi) {
            #pragma unroll
            for (int ni = 0; ni < 4; ++ni)
                acc[mi][ni] = __builtin_amdgcn_mfma_i32_16x16x64_i8(a[mi], b[ni], acc[mi][ni], 0, 0, 0);
        }
        __builtin_amdgcn_s_setprio(0);
        BARRIER();

        // ---- phase 1 ----
        i32x4 a2[4];
        #pragma unroll
        for (int mi = 0; mi < 4; ++mi) a2[mi] = *(const i32x4*)(L + offA[4 + mi]);
        if (st) { GLD16(gB0 + k2, Ls + 16384 + ldst); GLD16(gB1 + k2, Ls + 24576 + ldst); }
        BARRIER();
        __builtin_amdgcn_s_setprio(1);
        #pragma unroll
        for (int mi = 0; mi < 4; ++mi) {
            #pragma unroll
            for (int ni = 0; ni < 4; ++ni)
                acc[4 + mi][ni] = __builtin_amdgcn_mfma_i32_16x16x64_i8(a2[mi], b[ni], acc[4 + mi][ni], 0, 0, 0);
        }
        __builtin_amdgcn_s_setprio(0);
        if (st) { asm volatile("s_waitcnt vmcnt(4)" ::: "memory"); }
        else    { asm volatile("s_waitcnt vmcnt(0)" ::: "memory"); }
        BARRIER();
    }

    const float s_h = sh[0];
    #pragma unroll
    for (int ni = 0; ni < 4; ++ni) {
        const int n = n0 + wn * 64 + ni * 16 + lr;
        const float f = s_h * sw[n];
        #pragma unroll
        for (int mi = 0; mi < 8; ++mi) {
            const int mb = m0 + wm * 128 + mi * 16 + lk * 4;
            #pragma unroll
            for (int r = 0; r < 4; ++r)
                Out[(size_t)(mb + r) * N + n] = (float)acc[mi][ni][r] * f;
        }
    }
}

extern "C" void kernel_launch(void* const* d_in, const int* in_sizes, int n_in,
                              void* d_out, int out_size, void* d_ws, size_t ws_size,
                              hipStream_t stream) {
    const float* x       = (const float*)d_in[0];
    const float* clip_x  = (const float*)d_in[1];
    const float* clip_dn = (const float*)d_in[2];
    const float* w_gate  = (const float*)d_in[3];
    const float* w_up    = (const float*)d_in[4];
    const float* w_down  = (const float*)d_in[5];
    float* out = (float*)d_out;

    const int Hd = 1024, Id = 2816;
    const int M = in_sizes[0] / Hd;                  // 65536
    const size_t nx = (size_t)M * Hd;
    const size_t nh = (size_t)M * Id;

    char* ws = (char*)d_ws;
    size_t off = 0;
    auto alloc = [&](size_t bytes) -> char* {
        char* p = ws + off;
        off = (off + bytes + 255) & ~(size_t)255;
        return p;
    };
    unsigned int* max_slots = (unsigned int*)alloc(8);   // [0]=max|x|, [1]=max|h|
    float* sxp = (float*)alloc(8);                       // [0]=scale, [1]=1/scale
    float* shp = (float*)alloc(8);
    int8_t* qx  = (int8_t*)alloc(nx);
    int8_t* qwg = (int8_t*)alloc((size_t)Id * Hd);
    int8_t* qwu = (int8_t*)alloc((size_t)Id * Hd);
    int8_t* qwd = (int8_t*)alloc((size_t)Hd * Id);
    float* swg = (float*)alloc((size_t)Id * 4);
    float* swu = (float*)alloc((size_t)Id * 4);
    float* swd = (float*)alloc((size_t)Hd * 4);
    int8_t* qh = (int8_t*)alloc(nh);
    float* hbuf = (float*)alloc(nh * 4);

    hipMemsetAsync(max_slots, 0, 8, stream);

    k_absmax<<<4096, 256, 0, stream>>>(x, nx / 4, &max_slots[0]);
    k_scale<<<1, 1, 0, stream>>>(clip_x, &max_slots[0], sxp);
    k_quant_f32_i8<<<2048, 256, 0, stream>>>(x, (int4*)qx, sxp, nx / 16);
    k_quant_w_i8<<<Id, 256, 0, stream>>>(w_gate, qwg, swg, Hd);
    k_quant_w_i8<<<Id, 256, 0, stream>>>(w_up, qwu, swu, Hd);
    k_quant_w_i8<<<Hd, 256, 0, stream>>>(w_down, qwd, swd, Id);

    k_gemm1_i8<<<(M / 256) * (Id / 128), 512, 0, stream>>>(qx, qwg, qwu, swg, swu, sxp,
                                                           hbuf, &max_slots[1]);
    k_scale<<<1, 1, 0, stream>>>(clip_dn, &max_slots[1], shp);
    k_quant_f32_i8<<<4096, 256, 0, stream>>>(hbuf, (int4*)qh, shp, nh / 16);

    k_gemm2_i8<<<(M / 256) * (Hd / 256), 512, 0, stream>>>(qh, qwd, swd, shp, out);
}